// Round 1
// baseline (187.201 us; speedup 1.0000x reference)
//
#include <hip/hip_runtime.h>
#include <hip/hip_bf16.h>
#include <stdint.h>

typedef __attribute__((ext_vector_type(8))) short short8;
typedef __attribute__((ext_vector_type(4))) float f32x4;
typedef __attribute__((ext_vector_type(4))) unsigned int u32x4;
typedef __attribute__((ext_vector_type(2))) unsigned int u32x2;

// Skeleton (fixed in reference)
__constant__ __align__(16) int NBRC[17][4] = {
    {7, 1, 4, 0}, {0, 2, 0, 0}, {1, 3, 0, 0}, {2, 0, 0, 0},
    {0, 5, 0, 0}, {4, 6, 0, 0}, {5, 0, 0, 0}, {0, 8, 0, 0},
    {7, 9, 11, 14}, {8, 10, 0, 0}, {9, 0, 0, 0}, {8, 12, 0, 0},
    {11, 13, 0, 0}, {12, 0, 0, 0}, {8, 15, 0, 0}, {14, 16, 0, 0},
    {15, 0, 0, 0}};
__constant__ int DEGC[17] = {3,2,2,1,2,2,1,2,4,2,1,2,2,1,2,2,1};
__constant__ float RDEGC[5] = {0.f, 1.f, 0.5f, 0.33333334f, 0.25f};
// per-wave output-joint-tile assignment, balanced so sum(deg) = 8 per wave
__constant__ int WNT[4] = {3, 4, 5, 5};
__constant__ int WJT[4][5] = {{8, 1, 2, 0, 0},
                              {0, 4, 5, 3, 0},
                              {7, 9, 11, 6, 10},
                              {12, 14, 15, 13, 16}};

__device__ inline unsigned short f2bf(float f) {
  union { float f; uint32_t u; } v; v.f = f;
  uint32_t u = v.u;
  uint32_t r = u + 0x7fffu + ((u >> 16) & 1u);  // RNE
  return (unsigned short)(r >> 16);
}
// hardware v_cvt_pk_bf16_f32 (RNE), a in low 16, b in high 16
__device__ inline uint32_t pk2(float a, float b) {
  union { __hip_bfloat162 h; uint32_t u; } v;
  v.h = __float22bfloat162_rn(make_float2(a, b));
  return v.u;
}
__device__ inline f32x4 mfma16(short8 a, short8 b, f32x4 c) {
  return __builtin_amdgcn_mfma_f32_16x16x32_bf16(a, b, c, 0, 0, 0);
}

// ---------------- prep kernel (unchanged) ----------------
__global__ void prep(const float* __restrict__ W1,
                     const float* __restrict__ W2,
                     const float* __restrict__ Wp2,
                     const float* __restrict__ W3,
                     const float* __restrict__ Wp1,
                     const float* __restrict__ b3,
                     const float* __restrict__ bp1,
                     short* __restrict__ W1b,
                     short* __restrict__ W2b,
                     short* __restrict__ Wp2b,
                     short* __restrict__ Mb,
                     float* __restrict__ bp1p) {
  __shared__ float w3s[4096];
  __shared__ float Qs[256];
  const int tid = threadIdx.x;
  const int bx = blockIdx.x;
  if (bx < 272) {
    for (int q = tid; q < 4096; q += 256) w3s[q] = W3[q];
    {
      int ro = tid >> 6, k = tid & 63;
      int r = bx * 4 + ro;
      int f = r / 17, i = r - f * 17;
      int dj = DEGC[i];
      float s = 0.f;
#pragma unroll
      for (int t = 0; t < 4; t++) {
        if (t < dj) {
          int nb = NBRC[i][t];
          s += RDEGC[DEGC[nb]] * Wp1[f * 1088 + nb * 64 + k];
        }
      }
      Qs[ro * 64 + k] = s;
    }
    __syncthreads();
    {
      int ro = tid >> 6, c = tid & 63;
      int r = bx * 4 + ro;
      int f = r / 17, i = r - f * 17;
      float s = 0.f;
#pragma unroll
      for (int k = 0; k < 64; k++) s += Qs[ro * 64 + k] * w3s[k * 64 + c];
      int col = i * 64 + c;
      int kk = col >> 5, qq = (col >> 3) & 3, cb = col & 7;
      int w = f >> 4, l15 = f & 15;
      Mb[(((w * 34 + kk) * 64) + qq * 16 + l15) * 8 + cb] = (short)f2bf(s);
    }
  } else if (bx < 354) {
    int q = (bx - 272) * 256 + tid;
    if (q < 4096) W2b[q] = (short)f2bf(W2[q]);
    int q2 = q - 4096;
    if (q2 >= 0 && q2 < 16384) Wp2b[q2] = (short)f2bf(Wp2[q2]);
    int q3 = q - 20480;
    if (q3 >= 0 && q3 < 512) {
      int k = q3 & 7;
      W1b[q3] = (k < 3) ? (short)f2bf(W1[(q3 >> 3) * 3 + k]) : (short)0;
    }
  } else {
    int wv = tid >> 6, l = tid & 63;
    int f = (bx - 354) * 4 + wv;
    float s = 0.f;
#pragma unroll
    for (int i = 0; i < 17; i++) s += Wp1[f * 1088 + i * 64 + l] * b3[l];
#pragma unroll
    for (int off = 32; off > 0; off >>= 1) s += __shfl_down(s, off);
    if (l == 0) bp1p[f] = bp1[f] + s;
  }
}

// ---------------- main fused kernel ----------------
// 16 elements/block, 256 threads. hbuf stride-64 bf16, XOR-swizzled
// (byte ^= (row&7)<<4) — conflict-equivalent to the old stride-72 pad but
// 34816 B instead of 39168. agg0 lives in hbuf cols 0..3 (owner-wave-only
// read-before-overwrite in L1). W2 fragments come straight from global
// (L1-resident 8 KB). zb overlays the dead xs scratch. Total LDS 38848 B
// -> 4 blocks/CU with __launch_bounds__(256,4).
__launch_bounds__(256, 4)
__global__ void gcn_main(const float* __restrict__ X,
                         const short* __restrict__ Mb,
                         const short* __restrict__ Wp2b,
                         const short* __restrict__ W2b,
                         const short* __restrict__ W1b,
                         const float* __restrict__ bp1p,
                         const float* __restrict__ b1g,
                         const float* __restrict__ b2g,
                         const float* __restrict__ bp2g,
                         float* __restrict__ OUT) {
  __shared__ __align__(16) short hbuf[272 * 64];  // 34816 B
  __shared__ __align__(16) float xs[816];         // 3264 B; zb overlays late
  __shared__ __align__(16) float sbias[192];      // 768 B: b1|b2|bp1p

  const int tid = threadIdx.x;
  const int wave = tid >> 6;
  const int lane = tid & 63;
  const int ln15 = lane & 15;
  const int quad = lane >> 4;
  const int e0 = blockIdx.x * 16;

  char* hb = (char*)hbuf;
  auto hswz = [](int row, int cb) { return row * 128 + (cb ^ ((row & 7) << 4)); };

  // ---- init ----
  if (tid < 204) ((f32x4*)xs)[tid] = ((const f32x4*)(X + e0 * 51))[tid];
  short8 w1f[4];
#pragma unroll
  for (int ft = 0; ft < 4; ft++)
    w1f[ft] = *(const short8*)(W1b + (ft * 16 + ln15) * 8);
  if (tid < 192) {
    float v;
    if (tid < 64) v = b1g[tid];
    else if (tid < 128) v = b2g[tid - 64];
    else v = bp1p[tid - 128];
    sbias[tid] = v;
  }
  __syncthreads();

  // ---- agg0 = A@x (fp32), packed bf16 into hbuf row bytes 0..7 ----
  for (int q = tid; q < 272; q += 256) {
    int i = q >> 4, e = q & 15;
    int4 nb = *(const int4*)(&NBRC[i][0]);
    int dj = DEGC[i];
    float s0 = 0.f, s1 = 0.f, s2 = 0.f;
    {
      int b = e * 51 + nb.x * 3;
      s0 += xs[b]; s1 += xs[b + 1]; s2 += xs[b + 2];
    }
    if (dj > 1) {
      int b = e * 51 + nb.y * 3;
      s0 += xs[b]; s1 += xs[b + 1]; s2 += xs[b + 2];
    }
    if (dj > 2) {
      int b = e * 51 + nb.z * 3;
      s0 += xs[b]; s1 += xs[b + 1]; s2 += xs[b + 2];
    }
    if (dj > 3) {
      int b = e * 51 + nb.w * 3;
      s0 += xs[b]; s1 += xs[b + 1]; s2 += xs[b + 2];
    }
    float w = (dj == 1) ? 1.f : (dj == 2) ? 0.5f : (dj == 3) ? 0.33333334f : 0.25f;
    u32x2 pk;
    pk.x = pk2(s0 * w, s1 * w);
    pk.y = pk2(s2 * w, 0.f);
    *(u32x2*)(hb + hswz(q, 0)) = pk;
  }
  __syncthreads();

  auto wb = [&](f32x4 c, int j, int ft, int bofs, float scale) {
    int r = j * 16 + ln15;
    int fb = ft * 16 + quad * 4;
    f32x4 bv = *(const f32x4*)&sbias[bofs + fb];
    float v0 = fmaxf(c.x * scale + bv.x, 0.f);
    float v1 = fmaxf(c.y * scale + bv.y, 0.f);
    float v2 = fmaxf(c.z * scale + bv.z, 0.f);
    float v3 = fmaxf(c.w * scale + bv.w, 0.f);
    u32x2 pk;
    pk.x = pk2(v0, v1);
    pk.y = pk2(v2, v3);
    *(u32x2*)(hb + hswz(r, fb * 2)) = pk;
  };

  const int nt = WNT[wave];

  // ---- Layer 1: streamed per tile (acc liveness = one tile) ----
#pragma unroll
  for (int t = 0; t < 5; t++) {
    if (t < nt) {
      int j = WJT[wave][t];
      union { short8 s; u32x4 u; } fr;
      fr.u = (u32x4){0u, 0u, 0u, 0u};
      if (quad == 0) {
        u32x2 v = *(const u32x2*)(hb + hswz(j * 16 + ln15, 0));
        fr.u.x = v.x;
        fr.u.y = v.y;
      }
      f32x4 a[4];
#pragma unroll
      for (int ft = 0; ft < 4; ft++) {
        f32x4 z = (f32x4){0.f, 0.f, 0.f, 0.f};
        a[ft] = mfma16(w1f[ft], fr.s, z);
      }
#pragma unroll
      for (int ft = 0; ft < 4; ft++) wb(a[ft], j, ft, 0, 1.f);
    }
  }
  __syncthreads();  // h1 ready

  // ---- Layer 2: block-sparse MFMA aggregation, kk-outer (w2f = 16 regs) ----
  {
    f32x4 acc[5][4];
#pragma unroll
    for (int t = 0; t < 5; t++)
      if (t < nt)
#pragma unroll
        for (int ft = 0; ft < 4; ft++) acc[t][ft] = (f32x4){0.f, 0.f, 0.f, 0.f};
#pragma unroll
    for (int kk = 0; kk < 2; kk++) {
      short8 w2f[4];
#pragma unroll
      for (int ft = 0; ft < 4; ft++)
        w2f[ft] = *(const short8*)(W2b + (ft * 16 + ln15) * 64 + kk * 32 + quad * 8);
#pragma unroll
      for (int t = 0; t < 5; t++) {
        if (t < nt) {
          int j = WJT[wave][t];
          int dj = DEGC[j];
#pragma unroll
          for (int s = 0; s < 4; s++) {
            if (s < dj) {
              int i = NBRC[j][s];
              short8 bf = *(const short8*)(hb + hswz(i * 16 + ln15, kk * 64 + quad * 16));
#pragma unroll
              for (int ft = 0; ft < 4; ft++)
                acc[t][ft] = mfma16(w2f[ft], bf, acc[t][ft]);
            }
          }
        }
      }
    }
    __syncthreads();  // all h1 reads done before overwrite
#pragma unroll
    for (int t = 0; t < 5; t++)
      if (t < nt) {
        int j = WJT[wave][t];
        int dj = DEGC[j];
        float w = (dj == 1) ? 1.f : (dj == 2) ? 0.5f : (dj == 3) ? 0.33333334f : 0.25f;
#pragma unroll
        for (int ft = 0; ft < 4; ft++) wb(acc[t][ft], j, ft, 64, w);
      }
  }
  __syncthreads();  // h2 ready

  // ---- Pool (folded layer3+pool1), Mb swizzled + software-pipelined ----
  f32x4 zc;
  {
    const short8* mrow = ((const short8*)Mb) + (size_t)wave * 34 * 64 + lane;
    f32x4 accA = (f32x4){0.f, 0.f, 0.f, 0.f};
    f32x4 accB = (f32x4){0.f, 0.f, 0.f, 0.f};
    short8 pf[8];
#pragma unroll
    for (int p = 0; p < 8; p++) pf[p] = mrow[p * 64];
#pragma unroll
    for (int kk = 0; kk < 34; kk++) {
      short8 af = pf[kk & 7];
      if (kk + 8 < 34) pf[kk & 7] = mrow[(kk + 8) * 64];
      int i = kk >> 1;
      short8 bf = *(const short8*)(hb + hswz(i * 16 + ln15, (kk & 1) * 64 + quad * 16));
      if (kk & 1) accB = mfma16(af, bf, accB);
      else accA = mfma16(af, bf, accA);
    }
    zc = accA + accB;
  }
  // prefetch Wp2 fragments; latency hides behind zb pack + barrier
  short8 wp2f[4][2];
#pragma unroll
  for (int t = 0; t < 4; t++) {
    int ot = wave + 4 * t;
    wp2f[t][0] = *(const short8*)(Wp2b + (ot * 16 + ln15) * 64 + quad * 8);
    wp2f[t][1] = *(const short8*)(Wp2b + (ot * 16 + ln15) * 64 + 32 + quad * 8);
  }
  char* zbB = (char*)xs;  // overlay: xs dead since agg0 (4 barriers ago)
  {
    int fb = wave * 16 + quad * 4;
    f32x4 bv = *(const f32x4*)&sbias[128 + fb];
    float v0 = fmaxf(zc.x + bv.x, 0.f);
    float v1 = fmaxf(zc.y + bv.y, 0.f);
    float v2 = fmaxf(zc.z + bv.z, 0.f);
    float v3 = fmaxf(zc.w + bv.w, 0.f);
    u32x2 pk;
    pk.x = pk2(v0, v1);
    pk.y = pk2(v2, v3);
    *(u32x2*)(zbB + hswz(ln15, fb * 2)) = pk;
  }
  __syncthreads();

  // ---- Pool layer 2: out = Wp2 * z + bp2 ----
  {
    short8 bf0 = *(const short8*)(zbB + hswz(ln15, quad * 16));
    short8 bf1 = *(const short8*)(zbB + hswz(ln15, 64 + quad * 16));
#pragma unroll
    for (int t = 0; t < 4; t++) {
      int ot = wave + 4 * t;
      f32x4 a = (f32x4){0.f, 0.f, 0.f, 0.f};
      a = mfma16(wp2f[t][0], bf0, a);
      a = mfma16(wp2f[t][1], bf1, a);
      int ob = ot * 16 + quad * 4;
      f32x4 bv = *(const f32x4*)&bp2g[ob];
      f32x4 res = a + bv;
      *(f32x4*)(OUT + (size_t)(e0 + ln15) * 256 + ob) = res;
    }
  }
}

extern "C" void kernel_launch(void* const* d_in, const int* in_sizes, int n_in,
                              void* d_out, int out_size, void* d_ws, size_t ws_size,
                              hipStream_t stream) {
  const float* X = (const float*)d_in[0];
  const float* W1 = (const float*)d_in[2];
  const float* b1 = (const float*)d_in[3];
  const float* W2 = (const float*)d_in[4];
  const float* b2 = (const float*)d_in[5];
  const float* W3 = (const float*)d_in[6];
  const float* b3 = (const float*)d_in[7];
  const float* Wp1 = (const float*)d_in[8];
  const float* bp1 = (const float*)d_in[9];
  const float* Wp2 = (const float*)d_in[10];
  const float* bp2 = (const float*)d_in[11];
  float* OUT = (float*)d_out;
  const int B = in_sizes[0] / 51;

  char* ws = (char*)d_ws;
  short* Mb = (short*)(ws + 0);          // 64*1088*2 = 139264 (swizzled)
  short* Wp2b = (short*)(ws + 139264);   // 32768
  short* W2b = (short*)(ws + 172032);    // 8192
  short* W1b = (short*)(ws + 180224);    // 1024
  float* bp1p = (float*)(ws + 181248);   // 256

  prep<<<370, 256, 0, stream>>>(W1, W2, Wp2, W3, Wp1, b3, bp1,
                                W1b, W2b, Wp2b, Mb, bp1p);
  gcn_main<<<B / 16, 256, 0, stream>>>(X, Mb, Wp2b, W2b, W1b, bp1p,
                                       b1, b2, bp2, OUT);
}